// Round 3
// baseline (242.037 us; speedup 1.0000x reference)
//
#include <hip/hip_runtime.h>

// ZeroPad2d: in [32,2048,2048] f32 -> out [32,2050,2050] f32, pad=1.
// R3: fat persistent blocks + deep MLP + nontemporal streaming.
//   - 2048 bulk blocks x 256 threads; each block copies 32 input rows
//     (unroll 4 -> 8 independent 16B loads in flight per thread)
//   - loads 16B-aligned; stores 16B-wide at 4B alignment (output interior
//     starts at +1 float) via aligned(4) vector type
//   - nontemporal hints on both streams (touch-once data, don't cache)
//   - 64 trailing blocks zero the top/bottom pad rows; lane 0 writes the
//     left/right border zeros per row
// Every output element is written on every call (harness does not re-poison).

#define CH 32
#define H  2048
#define W  2048
#define HPAD 2050
#define WPAD 2050
#define ROWS_PER_BLOCK 32
#define BULK_BLOCKS ((CH * H) / ROWS_PER_BLOCK)   // 2048

typedef float f32x4  __attribute__((ext_vector_type(4)));
typedef float f32x4u __attribute__((ext_vector_type(4), aligned(4)));

__global__ __launch_bounds__(256) void zeropad_rows(const float* __restrict__ in,
                                                    float* __restrict__ out) {
    const unsigned bid = blockIdx.x;
    const unsigned t   = threadIdx.x;

    if (bid < BULK_BLOCKS) {
        const unsigned row0 = bid * ROWS_PER_BLOCK;
        #pragma unroll 4
        for (unsigned i = 0; i < ROWS_PER_BLOCK; ++i) {
            const unsigned row = row0 + i;
            const unsigned c = row >> 11;           // row / 2048
            const unsigned h = row & 2047u;         // row % 2048
            const float* src = in + ((size_t)row << 11);
            float*       dst = out + (size_t)(c * HPAD + h + 1u) * WPAD + 1u;

            // 2048 floats/row = 512 chunks; thread t takes chunks t, t+256
            f32x4 a = __builtin_nontemporal_load((const f32x4*)(src + 4u * t));
            f32x4 b = __builtin_nontemporal_load((const f32x4*)(src + 4u * t + 1024u));
            __builtin_nontemporal_store(a, (f32x4u*)(dst + 4u * t));
            __builtin_nontemporal_store(b, (f32x4u*)(dst + 4u * t + 1024u));

            if (t == 0) {
                dst[-1]   = 0.f;   // left pad (x = 0)
                dst[2048] = 0.f;   // right pad (x = 2049)
            }
        }
    } else {
        // top/bottom zero pad rows: 32 channels x 2 rows
        const unsigned idx = bid - BULK_BLOCKS;     // 0..63
        const unsigned c   = idx >> 1;
        const unsigned y   = (idx & 1u) ? (HPAD - 1u) : 0u;
        float* dst = out + (size_t)(c * HPAD + y) * WPAD;

        f32x4 z = (f32x4)0.f;
        __builtin_nontemporal_store(z, (f32x4u*)(dst + 8u * t));
        __builtin_nontemporal_store(z, (f32x4u*)(dst + 8u * t + 4u));
        if (t == 0) {
            dst[2048] = 0.f;
            dst[2049] = 0.f;
        }
    }
}

extern "C" void kernel_launch(void* const* d_in, const int* in_sizes, int n_in,
                              void* d_out, int out_size, void* d_ws, size_t ws_size,
                              hipStream_t stream) {
    const float* in = (const float*)d_in[0];
    float* out = (float*)d_out;
    const int blocks = BULK_BLOCKS + CH * 2;        // 2048 bulk + 64 pad-row blocks
    zeropad_rows<<<blocks, 256, 0, stream>>>(in, out);
}

// Round 4
// 193.045 us; speedup vs baseline: 1.2538x; 1.2538x over previous
//
#include <hip/hip_runtime.h>

// ZeroPad2d: in [32,2048,2048] f32 -> out [32,2050,2050] f32, pad=1.
// R4: R2 structure (1 row / 256-thread block, no nontemporal) but with
// 16B-ALIGNED STORES and misaligned loads (reads tolerate misalignment;
// misaligned stores cost partial-line RMW + extra store transactions).
//
// Padded row start s = (c*2050+h+1)*2050 is always even; s%4 in {0,2}.
//   p = (s%4)/2; body = out + s + 2p is 16B-aligned.
//   body chunk k (k=0..511, f32x4, aligned) = src[4k+2p-1 .. 4k+2p+2],
//   except the row-edge chunk (k=0 when p=0, k=511 when p=1) which holds a
//   pad zero and is built from scalars by its owning lane.
//   lane 0 writes the leftover 2 floats (head when p=1, tail when p=0).
// 64 trailing blocks zero the top/bottom pad rows.
// Every output element is written on every call (harness does not re-poison).

#define CH 32
#define H  2048
#define W  2048
#define HPAD 2050
#define WPAD 2050

typedef float f32x4 __attribute__((ext_vector_type(4)));
typedef float f32x2 __attribute__((ext_vector_type(2)));

__global__ __launch_bounds__(256) void zeropad_rows(const float* __restrict__ in,
                                                    float* __restrict__ out) {
    const unsigned bid = blockIdx.x;
    const unsigned t   = threadIdx.x;

    if (bid < CH * H) {
        const unsigned c = bid >> 11;            // row / 2048
        const unsigned h = bid & 2047u;          // row % 2048
        const float* src = in + ((size_t)bid << 11);
        const size_t  s  = (size_t)(c * HPAD + h + 1u) * WPAD;  // padded-row start
        float* dstrow    = out + s;
        const unsigned p = ((unsigned)s & 3u) >> 1;             // 0 or 2-float shift
        float* body      = dstrow + 2u * p;                     // 16B-aligned
        const float* ls  = src + 2u * p;                        // body k reads ls[4k-1..4k+2]

        #pragma unroll
        for (int kk = 0; kk < 2; ++kk) {
            const unsigned k = t + 256u * kk;                   // 0..511
            f32x4 v;
            const bool edge = (p == 0u) ? (k == 0u) : (k == 511u);
            if (!edge) {
                __builtin_memcpy(&v, ls + 4u * k - 1u, 16);     // 4B-aligned 16B load
            } else if (p == 0u) {
                v[0] = 0.f;       v[1] = src[0];    v[2] = src[1];    v[3] = src[2];
            } else {
                v[0] = src[2045]; v[1] = src[2046]; v[2] = src[2047]; v[3] = 0.f;
            }
            *(f32x4*)(body + 4u * k) = v;                       // 16B-aligned store
        }
        if (t == 0) {
            if (p == 0u) { dstrow[2048] = src[2047]; dstrow[2049] = 0.f; }
            else         { dstrow[0]    = 0.f;       dstrow[1]    = src[0]; }
        }
    } else {
        // top/bottom zero pad rows: 32 channels x 2 rows, 2050 zeros each
        const unsigned idx = bid - CH * H;        // 0..63
        const unsigned c   = idx >> 1;
        const unsigned y   = (idx & 1u) ? (HPAD - 1u) : 0u;
        float* dst = out + (size_t)(c * HPAD + y) * WPAD;       // always 8B-aligned

        const f32x2 z2 = (f32x2)0.f;
        #pragma unroll
        for (int kk = 0; kk < 4; ++kk) {
            const unsigned k = t + 256u * kk;                   // 0..1023 (f32x2 chunks)
            *(f32x2*)(dst + 2u * k) = z2;                       // 8B-aligned store
        }
        if (t == 0) { dst[2048] = 0.f; dst[2049] = 0.f; }
    }
}

extern "C" void kernel_launch(void* const* d_in, const int* in_sizes, int n_in,
                              void* d_out, int out_size, void* d_ws, size_t ws_size,
                              hipStream_t stream) {
    const float* in = (const float*)d_in[0];
    float* out = (float*)d_out;
    const int blocks = CH * H + CH * 2;           // 65536 copy rows + 64 pad rows
    zeropad_rows<<<blocks, 256, 0, stream>>>(in, out);
}